// Round 2
// baseline (1053.714 us; speedup 1.0000x reference)
//
#include <hip/hip_runtime.h>
#include <hip/hip_bf16.h>

// Problem constants
constexpr int kB   = 2;
constexpr int kL   = 96;
constexpr int kH   = 2;
constexpr int kE   = 63;
constexpr int kOUT = 256;
constexpr int kC1  = 64;
constexpr int kC2  = 128;
constexpr int kKS  = 3;
constexpr int kC   = 192;     // E + 1 + CONV2
constexpr int kLT  = 94;      // L - KS + 1
constexpr int kN   = 187;     // 2*LT - 1
constexpr int kTAU = 93;      // distinct signature steps (odd lead-lag increments are zero!)
constexpr int kEV  = 64;
constexpr int kBH  = 4;
constexpr int kSIG = 37056;   // C + C*C
constexpr int kNCOL = kBH * kTAU;  // 372 GEMM columns per W

// GEMM tiling
constexpr int KSPL = 6;
constexpr int KCH  = kSIG / KSPL; // 6176
constexpr int KT   = 32;
constexpr int NTILES = 6;         // ceil(372/64)

// Workspace layout (floats)
constexpr size_t AUG_OFF  = 0;
constexpr size_t AUG_SZ   = (size_t)2 * kBH * kLT * kC;    // 144384
constexpr size_t D_OFF    = AUG_OFF + AUG_SZ;
constexpr size_t D_SZ     = (size_t)2 * kBH * kTAU * kC;   // 142848
constexpr size_t U_OFF    = D_OFF + D_SZ;
constexpr size_t F_OFF    = U_OFF + D_SZ;
constexpr size_t F_SZ     = (size_t)2 * kBH * kTAU * kOUT; // 190464
constexpr size_t VAGG_OFF = F_OFF + F_SZ;

// ---------------------------------------------------------------------------
// Kernel A: augment = [trunc(63) | time(1) | relu(conv2(conv1(x)))(128)]
// grid (94 t, 4 bh, 2 qk), 192 threads
// ---------------------------------------------------------------------------
__global__ __launch_bounds__(192) void augment_kernel(
    const float* __restrict__ q, const float* __restrict__ k,
    const float* __restrict__ W1q, const float* __restrict__ b1q,
    const float* __restrict__ W2q, const float* __restrict__ b2q,
    const float* __restrict__ W1k, const float* __restrict__ b1k,
    const float* __restrict__ W2k, const float* __restrict__ b2k,
    float* __restrict__ aug)
{
    const int t  = blockIdx.x;   // 0..93
    const int bh = blockIdx.y;   // 0..3
    const int qk = blockIdx.z;   // 0 = q, 1 = k
    const int tid = threadIdx.x;

    const float* x  = qk ? k   : q;
    const float* W1 = qk ? W1k : W1q;
    const float* b1 = qk ? b1k : b1q;
    const float* W2 = qk ? W2k : W2q;
    const float* b2 = qk ? b2k : b2q;

    __shared__ float xwin[kKS][kE];
    __shared__ float hbuf[kC1];

    const int b = bh >> 1, h = bh & 1;
    if (tid < kKS * kE) {
        int s = tid / kE, e = tid - s * kE;
        // x[bh, t+s, e] = q[b, t+s, h, e]
        xwin[s][e] = x[(((size_t)b * kL + (t + s)) * kH + h) * kE + e];
    }
    __syncthreads();

    if (tid < kC1) {
        float acc = b1[tid];
        const float* wrow = W1 + (size_t)tid * kE * kKS;  // (o1, e, s)
        #pragma unroll 3
        for (int s = 0; s < kKS; s++)
            for (int e = 0; e < kE; e++)
                acc += xwin[s][e] * wrow[e * kKS + s];
        hbuf[tid] = acc;
    }
    __syncthreads();

    float* augrow = aug + ((size_t)(qk * kBH + bh) * kLT + t) * kC;
    if (tid < kC2) {
        float acc = b2[tid];
        const float* wrow = W2 + (size_t)tid * kC1;
        for (int o1 = 0; o1 < kC1; o1++)
            acc += hbuf[o1] * wrow[o1];
        augrow[kE + 1 + tid] = fmaxf(acc, 0.0f);
    }
    if (tid < kE) augrow[tid] = xwin[kKS - 1][tid];   // trunc = x[t+2]
    if (tid == kE) augrow[kE] = (float)t * (1.0f / 93.0f);  // time
}

// ---------------------------------------------------------------------------
// Kernel B: d[tau] = aug[tau+1]-aug[tau]; u[tau] = cumsum(d) - 0.5 d
// grid (4 bh, 2 qk), 192 threads (one per channel)
// ---------------------------------------------------------------------------
__global__ __launch_bounds__(192) void diffcum_kernel(
    const float* __restrict__ aug, float* __restrict__ dArr, float* __restrict__ uArr)
{
    const int bh = blockIdx.x, qk = blockIdx.y;
    const int c = threadIdx.x;
    const float* a = aug + (size_t)(qk * kBH + bh) * kLT * kC;
    float* dp = dArr + (size_t)(qk * kBH + bh) * kTAU * kC;
    float* up = uArr + (size_t)(qk * kBH + bh) * kTAU * kC;
    float run = 0.f;
    float prev = a[c];
    for (int tau = 0; tau < kTAU; tau++) {
        float nxt = a[(size_t)(tau + 1) * kC + c];
        float dd = nxt - prev;
        run += dd;
        dp[(size_t)tau * kC + c] = dd;
        up[(size_t)tau * kC + c] = run - 0.5f * dd;
        prev = nxt;
    }
}

// ---------------------------------------------------------------------------
// Kernel C: F[qk, n, o] = sum_k W[o,k] * X[n,k],
//   X[n, k<192] = d[n,k];  X[n, 192 + i*192 + j] = u[n,i]*d[n,j]
// GEMM M=256, N=372, K=37056; 64x64 tiles, split-K=6, atomicAdd into F.
// grid (4 otile, 6 ntile, 12 = qk*6 + ks), 256 threads
// ---------------------------------------------------------------------------
__global__ __launch_bounds__(256) void sigproj_kernel(
    const float* __restrict__ Wlq,
    const float* __restrict__ Wlk,
    const float* __restrict__ dArr,
    const float* __restrict__ uArr,
    float* __restrict__ F)
{
    const int otile = blockIdx.x;
    const int ntile = blockIdx.y;
    const int zz = blockIdx.z;
    const int qk = zz / KSPL;
    const int ks = zz - qk * KSPL;

    const float* __restrict__ W = qk ? Wlk : Wlq;
    const float* dB = dArr + (size_t)qk * kNCOL * kC;
    const float* uB = uArr + (size_t)qk * kNCOL * kC;

    __shared__ __align__(16) float Ws[64][36];  // [o][k], pad to 36
    __shared__ __align__(16) float Xs[64][36];  // [n][k]

    const int tid = threadIdx.x;
    const int tx = tid & 15;
    const int ty = tid >> 4;

    // W staging: each thread loads 8 consecutive floats (2x float4) of one o-row
    const int so = tid >> 2;
    const int sk = (tid & 3) * 8;
    const float* Wrow = W + (size_t)(otile * 64 + so) * kSIG;

    // X staging: each thread generates 8 consecutive k for one column n
    const int xn = tid & 63;
    const int xk = (tid >> 6) * 8;
    const int ngx = ntile * 64 + xn;
    const bool xval = ngx < kNCOL;
    const float* dn = dB + (size_t)(xval ? ngx : 0) * kC;
    const float* un = uB + (size_t)(xval ? ngx : 0) * kC;

    float acc[4][4];
    #pragma unroll
    for (int a = 0; a < 4; a++)
        #pragma unroll
        for (int bb = 0; bb < 4; bb++) acc[a][bb] = 0.f;

    const int kbeg = ks * KCH, kend = kbeg + KCH;
    for (int kb = kbeg; kb < kend; kb += KT) {
        {
            float4 w0 = *reinterpret_cast<const float4*>(Wrow + kb + sk);
            float4 w1 = *reinterpret_cast<const float4*>(Wrow + kb + sk + 4);
            *reinterpret_cast<float4*>(&Ws[so][sk])     = w0;
            *reinterpret_cast<float4*>(&Ws[so][sk + 4]) = w1;
        }
        #pragma unroll
        for (int j = 0; j < 8; j++) {
            int kg = kb + xk + j;
            float val;
            if (kg < kC) {
                val = dn[kg];
            } else {
                unsigned int m = (unsigned int)(kg - kC);
                unsigned int ii = m / 192u;
                unsigned int jj = m - ii * 192u;
                val = un[ii] * dn[jj];
            }
            Xs[xn][xk + j] = xval ? val : 0.f;
        }
        __syncthreads();

        #pragma unroll
        for (int k4 = 0; k4 < KT / 4; k4++) {
            const int kk = k4 * 4;
            float4 xv[4], wv[4];
            #pragma unroll
            for (int bb = 0; bb < 4; bb++)
                xv[bb] = *reinterpret_cast<const float4*>(&Xs[bb * 16 + tx][kk]);
            #pragma unroll
            for (int a = 0; a < 4; a++)
                wv[a] = *reinterpret_cast<const float4*>(&Ws[a * 16 + ty][kk]);
            #pragma unroll
            for (int a = 0; a < 4; a++)
                #pragma unroll
                for (int bb = 0; bb < 4; bb++)
                    acc[a][bb] += wv[a].x * xv[bb].x + wv[a].y * xv[bb].y +
                                  wv[a].z * xv[bb].z + wv[a].w * xv[bb].w;
        }
        __syncthreads();
    }

    #pragma unroll
    for (int a = 0; a < 4; a++) {
        const int o = otile * 64 + a * 16 + ty;
        #pragma unroll
        for (int bb = 0; bb < 4; bb++) {
            const int ng = ntile * 64 + bb * 16 + tx;
            if (ng < kNCOL)
                atomicAdd(&F[((size_t)qk * kNCOL + ng) * kOUT + o], acc[a][bb]);
        }
    }
}

// ---------------------------------------------------------------------------
// Kernel D: P[qk, bh, tau, o] = bias[o] + cumsum_tau F   (in place)
// grid (4 bh, 2 qk), 256 threads (one per o)
// ---------------------------------------------------------------------------
__global__ __launch_bounds__(256) void cumsum_kernel(
    float* __restrict__ F,
    const float* __restrict__ blq, const float* __restrict__ blk)
{
    const int bh = blockIdx.x, qk = blockIdx.y;
    const int o = threadIdx.x;
    float run = (qk ? blk : blq)[o];
    float* base = F + ((size_t)qk * kNCOL + bh * kTAU) * kOUT + o;
    for (int tau = 0; tau < kTAU; tau++) {
        run += base[(size_t)tau * kOUT];
        base[(size_t)tau * kOUT] = run;
    }
}

// ---------------------------------------------------------------------------
// Kernel E: vagg[bh, tau, e] = v[bh,2tau,e] + v[bh,2tau+1,e] (+ v[bh,186,e] at tau=92)
// grid (93 tau, 4 bh), 64 threads
// ---------------------------------------------------------------------------
__global__ __launch_bounds__(64) void vagg_kernel(
    const float* __restrict__ v, float* __restrict__ vagg)
{
    const int tau = blockIdx.x, bh = blockIdx.y, e = threadIdx.x;
    const float* vb = v + ((size_t)bh * kN + 2 * tau) * kEV + e;
    float s = vb[0] + vb[kEV];
    if (tau == kTAU - 1) s += vb[2 * kEV];
    vagg[((size_t)bh * kTAU + tau) * kEV + e] = s;
}

// ---------------------------------------------------------------------------
// Kernel F: A[sg,t] = tanh(QP[sg]·KP[t]); OutU = A @ vagg; scatter duplicated rows
// grid (93 sigma, 4 bh), 128 threads
// ---------------------------------------------------------------------------
__global__ __launch_bounds__(128) void attn_kernel(
    const float* __restrict__ P, const float* __restrict__ vagg,
    float* __restrict__ out)
{
    const int sg = blockIdx.x;   // 0..92
    const int bh = blockIdx.y;   // 0..3
    const int tid = threadIdx.x;

    __shared__ float q_l[kOUT];
    __shared__ __align__(16) float kp_l[kTAU][65];
    __shared__ float A_l[kTAU];

    const float* qrow = P + ((size_t)bh * kTAU + sg) * kOUT;
    q_l[tid] = qrow[tid];
    q_l[tid + 128] = qrow[tid + 128];

    const float* kbase = P + ((size_t)kNCOL + bh * kTAU) * kOUT;
    const int ri = tid >> 6;  // 0..1
    const int oi = tid & 63;
    float dot = 0.f;
    for (int oc = 0; oc < kOUT; oc += 64) {
        __syncthreads();
        for (int t = ri; t < kTAU; t += 2)
            kp_l[t][oi] = kbase[(size_t)t * kOUT + oc + oi];
        __syncthreads();
        if (tid < kTAU) {
            #pragma unroll 8
            for (int i = 0; i < 64; i++)
                dot += q_l[oc + i] * kp_l[tid][i];
        }
    }
    if (tid < kTAU) A_l[tid] = tanhf(dot);
    __syncthreads();

    if (tid < kEV) {
        float acc2 = 0.f;
        const float* vb = vagg + (size_t)bh * kTAU * kEV + tid;
        for (int t = 0; t < kTAU; t++) acc2 += A_l[t] * vb[(size_t)t * kEV];
        const size_t rb = (size_t)bh * kN;
        out[(rb + 2 * sg) * kEV + tid] = acc2;
        out[(rb + 2 * sg + 1) * kEV + tid] = acc2;
        if (sg == kTAU - 1) out[(rb + 186) * kEV + tid] = acc2;
    }
}

// ---------------------------------------------------------------------------
extern "C" void kernel_launch(void* const* d_in, const int* in_sizes, int n_in,
                              void* d_out, int out_size, void* d_ws, size_t ws_size,
                              hipStream_t stream)
{
    (void)in_sizes; (void)n_in; (void)out_size; (void)ws_size;
    auto fp = [&](int i) { return (const float*)d_in[i]; };

    float* ws   = (float*)d_ws;
    float* aug  = ws + AUG_OFF;
    float* dArr = ws + D_OFF;
    float* uArr = ws + U_OFF;
    float* F    = ws + F_OFF;
    float* vagg = ws + VAGG_OFF;

    hipMemsetAsync(F, 0, F_SZ * sizeof(float), stream);

    augment_kernel<<<dim3(kLT, kBH, 2), 192, 0, stream>>>(
        fp(0), fp(1), fp(3), fp(4), fp(5), fp(6), fp(7), fp(8), fp(9), fp(10), aug);
    diffcum_kernel<<<dim3(kBH, 2), 192, 0, stream>>>(aug, dArr, uArr);
    sigproj_kernel<<<dim3(4, NTILES, 2 * KSPL), 256, 0, stream>>>(
        fp(11), fp(13), dArr, uArr, F);
    cumsum_kernel<<<dim3(kBH, 2), 256, 0, stream>>>(F, fp(12), fp(14));
    vagg_kernel<<<dim3(kTAU, kBH), 64, 0, stream>>>(fp(2), vagg);
    attn_kernel<<<dim3(kTAU, kBH), 128, 0, stream>>>(F, vagg, (float*)d_out);
}

// Round 4
// 478.426 us; speedup vs baseline: 2.2025x; 2.2025x over previous
//
#include <hip/hip_runtime.h>
#include <hip/hip_bf16.h>

// Problem constants
constexpr int kB   = 2;
constexpr int kL   = 96;
constexpr int kH   = 2;
constexpr int kE   = 63;
constexpr int kOUT = 256;
constexpr int kC1  = 64;
constexpr int kC2  = 128;
constexpr int kKS  = 3;
constexpr int kC   = 192;     // E + 1 + CONV2
constexpr int kLT  = 94;      // L - KS + 1
constexpr int kN   = 187;     // 2*LT - 1
constexpr int kTAU = 93;      // distinct signature steps (odd lead-lag increments are zero)
constexpr int kEV  = 64;
constexpr int kBH  = 4;
constexpr int kSIG = 37056;   // C + C*C
constexpr int kNCOL = kBH * kTAU;  // 372 GEMM columns per W

// GEMM tiling (MFMA)
constexpr int BK   = 32;
constexpr int NKB  = kSIG / BK;   // 1158 K-blocks
constexpr int KSPL = 24;          // split-K -> 4*6*24*2 = 1152 blocks
constexpr int NTILES = 6;         // ceil(372/64)

// Workspace layout (floats)
constexpr size_t AUG_OFF  = 0;
constexpr size_t AUG_SZ   = (size_t)2 * kBH * kLT * kC;    // 144384
constexpr size_t D_OFF    = AUG_OFF + AUG_SZ;
constexpr size_t D_SZ     = (size_t)2 * kBH * kTAU * kC;   // 142848
constexpr size_t U_OFF    = D_OFF + D_SZ;
constexpr size_t F_OFF    = U_OFF + D_SZ;
constexpr size_t F_SZ     = (size_t)2 * kBH * kTAU * kOUT; // 190464

typedef __attribute__((ext_vector_type(8))) short short8;
typedef __attribute__((ext_vector_type(4))) float f32x4;

__device__ __forceinline__ unsigned short f2bf(float x) {
    unsigned int u = __float_as_uint(x);
    unsigned int r = (u + 0x7FFFu + ((u >> 16) & 1u)) >> 16;  // RNE
    return (unsigned short)r;
}
__device__ __forceinline__ float bfbits2f(unsigned short u) {
    union { unsigned int i; float f; } c;
    c.i = ((unsigned int)u) << 16;
    return c.f;
}

// ---------------------------------------------------------------------------
// Kernel A: augment = [trunc(63) | time(1) | relu(conv2(conv1(x)))(128)]
// grid (94 t, 4 bh, 2 qk), 192 threads
// ---------------------------------------------------------------------------
__global__ __launch_bounds__(192) void augment_kernel(
    const float* __restrict__ q, const float* __restrict__ k,
    const float* __restrict__ W1q, const float* __restrict__ b1q,
    const float* __restrict__ W2q, const float* __restrict__ b2q,
    const float* __restrict__ W1k, const float* __restrict__ b1k,
    const float* __restrict__ W2k, const float* __restrict__ b2k,
    float* __restrict__ aug)
{
    const int t  = blockIdx.x;   // 0..93
    const int bh = blockIdx.y;   // 0..3
    const int qk = blockIdx.z;   // 0 = q, 1 = k
    const int tid = threadIdx.x;

    const float* x  = qk ? k   : q;
    const float* W1 = qk ? W1k : W1q;
    const float* b1 = qk ? b1k : b1q;
    const float* W2 = qk ? W2k : W2q;
    const float* b2 = qk ? b2k : b2q;

    __shared__ float xwin[kKS][kE];
    __shared__ float hbuf[kC1];

    const int b = bh >> 1, h = bh & 1;
    if (tid < kKS * kE) {
        int s = tid / kE, e = tid - s * kE;
        xwin[s][e] = x[(((size_t)b * kL + (t + s)) * kH + h) * kE + e];
    }
    __syncthreads();

    if (tid < kC1) {
        float acc = b1[tid];
        const float* wrow = W1 + (size_t)tid * kE * kKS;  // (o1, e, s)
        #pragma unroll 3
        for (int s = 0; s < kKS; s++)
            for (int e = 0; e < kE; e++)
                acc += xwin[s][e] * wrow[e * kKS + s];
        hbuf[tid] = acc;
    }
    __syncthreads();

    float* augrow = aug + ((size_t)(qk * kBH + bh) * kLT + t) * kC;
    if (tid < kC2) {
        float acc = b2[tid];
        const float* wrow = W2 + (size_t)tid * kC1;
        for (int o1 = 0; o1 < kC1; o1++)
            acc += hbuf[o1] * wrow[o1];
        augrow[kE + 1 + tid] = fmaxf(acc, 0.0f);
    }
    if (tid < kE) augrow[tid] = xwin[kKS - 1][tid];   // trunc = x[t+2]
    if (tid == kE) augrow[kE] = (float)t * (1.0f / 93.0f);  // time
}

// ---------------------------------------------------------------------------
// Kernel B: d[tau] = aug[tau+1]-aug[tau]; u[tau] = cumsum(d) - 0.5 d
// grid (4 bh, 2 qk), 192 threads (one per channel)
// ---------------------------------------------------------------------------
__global__ __launch_bounds__(192) void diffcum_kernel(
    const float* __restrict__ aug, float* __restrict__ dArr, float* __restrict__ uArr)
{
    const int bh = blockIdx.x, qk = blockIdx.y;
    const int c = threadIdx.x;
    const float* a = aug + (size_t)(qk * kBH + bh) * kLT * kC;
    float* dp = dArr + (size_t)(qk * kBH + bh) * kTAU * kC;
    float* up = uArr + (size_t)(qk * kBH + bh) * kTAU * kC;
    float run = 0.f;
    float prev = a[c];
    for (int tau = 0; tau < kTAU; tau++) {
        float nxt = a[(size_t)(tau + 1) * kC + c];
        float dd = nxt - prev;
        run += dd;
        dp[(size_t)tau * kC + c] = dd;
        up[(size_t)tau * kC + c] = run - 0.5f * dd;
        prev = nxt;
    }
}

// ---------------------------------------------------------------------------
// Kernel C (MFMA, 3-term bf16 split): F[qk, n, o] += sum_k W[o,k] * X[n,k]
//   X[n, k<192] = d[n,k];  X[n, 192 + i*192 + j] = u[n,i]*d[n,j]
//   w = w_hi + w_lo, x = x_hi + x_lo; acc += hi*hi + hi*lo + lo*hi (fp32 MFMA acc)
// grid (4 otile, 6 ntile, 48 = qk*24 + ks), 256 threads
// ---------------------------------------------------------------------------
__global__ __launch_bounds__(256) void sigproj_kernel(
    const float* __restrict__ Wlq,
    const float* __restrict__ Wlk,
    const float* __restrict__ dArr,
    const float* __restrict__ uArr,
    float* __restrict__ F)
{
    const int otile = blockIdx.x;
    const int ntile = blockIdx.y;
    const int zz = blockIdx.z;
    const int qk = zz / KSPL;
    const int ks = zz - qk * KSPL;

    const float* __restrict__ W = qk ? Wlk : Wlq;
    const float* dB = dArr + (size_t)qk * kNCOL * kC;
    const float* uB = uArr + (size_t)qk * kNCOL * kC;

    // row stride 40 bf16 = 80 B = 20 banks: <=2-way aliasing (free), 16B-aligned rows
    __shared__ __align__(16) unsigned short Ah[64][40];  // W hi
    __shared__ __align__(16) unsigned short Al[64][40];  // W lo
    __shared__ __align__(16) unsigned short Bh[64][40];  // X hi
    __shared__ __align__(16) unsigned short Bl[64][40];  // X lo

    const int tid  = threadIdx.x;
    const int lane = tid & 63;
    const int w    = tid >> 6;      // wave 0..3
    const int quad = lane >> 4;
    const int l16  = lane & 15;

    // staging: thread -> (row, 8 consecutive k)
    const int sr = tid >> 2;        // 0..63
    const int sk = (tid & 3) * 8;   // 0,8,16,24

    const float* Wrow = W + (size_t)(otile * 64 + sr) * kSIG;
    const int ng = ntile * 64 + sr;
    const bool nvalid = ng < kNCOL;
    const float* dn = dB + (size_t)(nvalid ? ng : 0) * kC;
    const float* un = uB + (size_t)(nvalid ? ng : 0) * kC;

    // K-range for this split (NKB BK-blocks over KSPL splits)
    const int kbase = NKB / KSPL, krem = NKB % KSPL;
    const int kb0 = ks * kbase + (ks < krem ? ks : krem);
    const int nkb = kbase + (ks < krem ? 1 : 0);

    f32x4 acc[2][2];
    #pragma unroll
    for (int a = 0; a < 2; a++)
        #pragma unroll
        for (int b = 0; b < 2; b++)
            acc[a][b] = (f32x4){0.f, 0.f, 0.f, 0.f};

    const int orow = (w & 1) * 32;   // wave's o-offset in tile
    const int ncol = (w >> 1) * 32;  // wave's n-offset in tile

    for (int kbi = 0; kbi < nkb; kbi++) {
        const int kb = (kb0 + kbi) * BK;

        // --- stage A: 64x32 W fp32 -> (hi, lo) bf16 LDS ---
        {
            float wf[8];
            *reinterpret_cast<float4*>(&wf[0]) =
                *reinterpret_cast<const float4*>(Wrow + kb + sk);
            *reinterpret_cast<float4*>(&wf[4]) =
                *reinterpret_cast<const float4*>(Wrow + kb + sk + 4);
            short8 hv, lv;
            #pragma unroll
            for (int j = 0; j < 8; j++) {
                unsigned short h = f2bf(wf[j]);
                hv[j] = (short)h;
                lv[j] = (short)f2bf(wf[j] - bfbits2f(h));
            }
            *reinterpret_cast<short8*>(&Ah[sr][sk]) = hv;
            *reinterpret_cast<short8*>(&Al[sr][sk]) = lv;
        }
        // --- stage B: generate 64x32 X -> (hi, lo) bf16 LDS ---
        {
            short8 hv, lv;
            #pragma unroll
            for (int j = 0; j < 8; j++) {
                int kg = kb + sk + j;
                float val;
                if (kg < kC) {
                    val = dn[kg];
                } else {
                    unsigned int m2 = (unsigned int)(kg - kC);
                    unsigned int ii = m2 / 192u;
                    unsigned int jj = m2 - ii * 192u;
                    val = un[ii] * dn[jj];
                }
                val = nvalid ? val : 0.f;
                unsigned short h = f2bf(val);
                hv[j] = (short)h;
                lv[j] = (short)f2bf(val - bfbits2f(h));
            }
            *reinterpret_cast<short8*>(&Bh[sr][sk]) = hv;
            *reinterpret_cast<short8*>(&Bl[sr][sk]) = lv;
        }
        __syncthreads();

        // --- MFMA: wave computes 32(o) x 32(n); 3 passes (hh, hl, lh) ---
        short8 afh[2], afl[2], bfh[2], bfl[2];
        #pragma unroll
        for (int a = 0; a < 2; a++) {
            afh[a] = *reinterpret_cast<const short8*>(&Ah[orow + a * 16 + l16][quad * 8]);
            afl[a] = *reinterpret_cast<const short8*>(&Al[orow + a * 16 + l16][quad * 8]);
        }
        #pragma unroll
        for (int b = 0; b < 2; b++) {
            bfh[b] = *reinterpret_cast<const short8*>(&Bh[ncol + b * 16 + l16][quad * 8]);
            bfl[b] = *reinterpret_cast<const short8*>(&Bl[ncol + b * 16 + l16][quad * 8]);
        }
        #pragma unroll
        for (int a = 0; a < 2; a++)
            #pragma unroll
            for (int b = 0; b < 2; b++) {
                acc[a][b] = __builtin_amdgcn_mfma_f32_16x16x32_bf16(
                    afh[a], bfh[b], acc[a][b], 0, 0, 0);
                acc[a][b] = __builtin_amdgcn_mfma_f32_16x16x32_bf16(
                    afh[a], bfl[b], acc[a][b], 0, 0, 0);
                acc[a][b] = __builtin_amdgcn_mfma_f32_16x16x32_bf16(
                    afl[a], bfh[b], acc[a][b], 0, 0, 0);
            }
        __syncthreads();
    }

    // --- epilogue: D row(o) = quad*4 + reg, col(n) = l16 (m89-verified) ---
    #pragma unroll
    for (int a = 0; a < 2; a++) {
        const int o = otile * 64 + orow + a * 16 + quad * 4;
        #pragma unroll
        for (int b = 0; b < 2; b++) {
            const int n = ntile * 64 + ncol + b * 16 + l16;
            if (n < kNCOL) {
                float* dst = F + ((size_t)qk * kNCOL + n) * kOUT + o;
                #pragma unroll
                for (int r = 0; r < 4; r++)
                    atomicAdd(dst + r, acc[a][b][r]);
            }
        }
    }
}

// ---------------------------------------------------------------------------
// Kernel D: P[qk, bh, tau, o] = bias[o] + cumsum_tau F   (in place)
// grid (4 bh, 2 qk), 256 threads (one per o)
// ---------------------------------------------------------------------------
__global__ __launch_bounds__(256) void cumsum_kernel(
    float* __restrict__ F,
    const float* __restrict__ blq, const float* __restrict__ blk)
{
    const int bh = blockIdx.x, qk = blockIdx.y;
    const int o = threadIdx.x;
    float run = (qk ? blk : blq)[o];
    float* base = F + ((size_t)qk * kNCOL + bh * kTAU) * kOUT + o;
    for (int tau = 0; tau < kTAU; tau++) {
        run += base[(size_t)tau * kOUT];
        base[(size_t)tau * kOUT] = run;
    }
}

// ---------------------------------------------------------------------------
// Kernel F: A[sg,t] = tanh(QP[sg]·KP[t]); Out = A @ (paired v); scatter dup rows
// grid (93 sigma, 4 bh), 128 threads.  (vagg fused: reads v directly)
// ---------------------------------------------------------------------------
__global__ __launch_bounds__(128) void attn_kernel(
    const float* __restrict__ P, const float* __restrict__ v,
    float* __restrict__ out)
{
    const int sg = blockIdx.x;   // 0..92
    const int bh = blockIdx.y;   // 0..3
    const int tid = threadIdx.x;

    __shared__ float q_l[kOUT];
    __shared__ __align__(16) float kp_l[kTAU][65];
    __shared__ float A_l[kTAU];

    const float* qrow = P + ((size_t)bh * kTAU + sg) * kOUT;
    q_l[tid] = qrow[tid];
    q_l[tid + 128] = qrow[tid + 128];

    const float* kbase = P + ((size_t)kNCOL + bh * kTAU) * kOUT;
    const int ri = tid >> 6;  // 0..1
    const int oi = tid & 63;
    float dot = 0.f;
    for (int oc = 0; oc < kOUT; oc += 64) {
        __syncthreads();
        for (int t = ri; t < kTAU; t += 2)
            kp_l[t][oi] = kbase[(size_t)t * kOUT + oc + oi];
        __syncthreads();
        if (tid < kTAU) {
            #pragma unroll 8
            for (int i = 0; i < 64; i++)
                dot += q_l[oc + i] * kp_l[tid][i];
        }
    }
    if (tid < kTAU) A_l[tid] = tanhf(dot);
    __syncthreads();

    if (tid < kEV) {
        const float* vb = v + (size_t)bh * kN * kEV + tid;
        float acc2 = 0.f;
        for (int t = 0; t < kTAU - 1; t++)
            acc2 += A_l[t] * (vb[(size_t)(2 * t) * kEV] + vb[(size_t)(2 * t + 1) * kEV]);
        acc2 += A_l[kTAU - 1] * (vb[(size_t)184 * kEV] + vb[(size_t)185 * kEV] +
                                 vb[(size_t)186 * kEV]);
        const size_t rb = (size_t)bh * kN;
        out[(rb + 2 * sg) * kEV + tid] = acc2;
        out[(rb + 2 * sg + 1) * kEV + tid] = acc2;
        if (sg == kTAU - 1) out[(rb + 186) * kEV + tid] = acc2;
    }
}

// ---------------------------------------------------------------------------
extern "C" void kernel_launch(void* const* d_in, const int* in_sizes, int n_in,
                              void* d_out, int out_size, void* d_ws, size_t ws_size,
                              hipStream_t stream)
{
    (void)in_sizes; (void)n_in; (void)out_size; (void)ws_size;
    auto fp = [&](int i) { return (const float*)d_in[i]; };

    float* ws   = (float*)d_ws;
    float* aug  = ws + AUG_OFF;
    float* dArr = ws + D_OFF;
    float* uArr = ws + U_OFF;
    float* F    = ws + F_OFF;

    hipMemsetAsync(F, 0, F_SZ * sizeof(float), stream);

    augment_kernel<<<dim3(kLT, kBH, 2), 192, 0, stream>>>(
        fp(0), fp(1), fp(3), fp(4), fp(5), fp(6), fp(7), fp(8), fp(9), fp(10), aug);
    diffcum_kernel<<<dim3(kBH, 2), 192, 0, stream>>>(aug, dArr, uArr);
    sigproj_kernel<<<dim3(4, NTILES, 2 * KSPL), 256, 0, stream>>>(
        fp(11), fp(13), dArr, uArr, F);
    cumsum_kernel<<<dim3(kBH, 2), 256, 0, stream>>>(F, fp(12), fp(14));
    attn_kernel<<<dim3(kTAU, kBH), 128, 0, stream>>>(F, fp(2), (float*)d_out);
}

// Round 5
// 354.984 us; speedup vs baseline: 2.9683x; 1.3477x over previous
//
#include <hip/hip_runtime.h>
#include <hip/hip_bf16.h>

// Problem constants
constexpr int kB   = 2;
constexpr int kL   = 96;
constexpr int kH   = 2;
constexpr int kE   = 63;
constexpr int kOUT = 256;
constexpr int kC1  = 64;
constexpr int kC2  = 128;
constexpr int kKS  = 3;
constexpr int kC   = 192;     // E + 1 + CONV2
constexpr int kLT  = 94;      // L - KS + 1
constexpr int kN   = 187;     // 2*LT - 1
constexpr int kTAU = 93;      // distinct signature steps (odd lead-lag increments are zero)
constexpr int kEV  = 64;
constexpr int kBH  = 4;
constexpr int kSIG = 37056;   // C + C*C = 193*192
constexpr int kNCOL = kBH * kTAU;  // 372 GEMM columns per W

// sigproj tiling: 193 "steps" of K=192 (step 0 = linear d part, step s>=1 scaled by u[:,s-1])
constexpr int NSTEP = 193;
constexpr int ISPL  = 24;         // step-split: grid z = 2*ISPL -> 4*6*48 = 1152 blocks
constexpr int NTILES = 6;         // ceil(372/64)

// Workspace layout (floats)
constexpr size_t AUG_OFF  = 0;
constexpr size_t AUG_SZ   = (size_t)2 * kBH * kLT * kC;    // 144384
constexpr size_t D_OFF    = AUG_OFF + AUG_SZ;
constexpr size_t D_SZ     = (size_t)2 * kBH * kTAU * kC;   // 142848
constexpr size_t U_OFF    = D_OFF + D_SZ;
constexpr size_t F_OFF    = U_OFF + D_SZ;
constexpr size_t F_SZ     = (size_t)2 * kBH * kTAU * kOUT; // 190464

typedef __attribute__((ext_vector_type(8))) short short8;
typedef __attribute__((ext_vector_type(4))) float f32x4;

__device__ __forceinline__ unsigned int fbits(float f) { return __float_as_uint(f); }
__device__ __forceinline__ float bitsf(unsigned int u) { return __uint_as_float(u); }

__device__ __forceinline__ unsigned short f2bf(float x) {
    unsigned int u = __float_as_uint(x);
    unsigned int r = (u + 0x7FFFu + ((u >> 16) & 1u)) >> 16;  // RNE
    return (unsigned short)r;
}
__device__ __forceinline__ float bfbits2f(unsigned short u) {
    return bitsf(((unsigned int)u) << 16);
}

union Pack8 { unsigned int u[4]; short8 v; };

// truncation hi/lo split of 8 fp32 -> two bf16x8 (cheap: ~4 VALU/elem)
__device__ __forceinline__ void split_trunc8(float4 x0, float4 x1, short8& hi, short8& lo) {
    float xf[8] = {x0.x, x0.y, x0.z, x0.w, x1.x, x1.y, x1.z, x1.w};
    Pack8 ph, pl;
    #pragma unroll
    for (int p = 0; p < 4; p++) {
        unsigned int ua = fbits(xf[2 * p]), ub = fbits(xf[2 * p + 1]);
        unsigned int ha = ua & 0xffff0000u, hb = ub & 0xffff0000u;
        ph.u[p] = (ua >> 16) | hb;
        float ra = xf[2 * p] - bitsf(ha);
        float rb = xf[2 * p + 1] - bitsf(hb);
        pl.u[p] = (fbits(ra) >> 16) | (fbits(rb) & 0xffff0000u);
    }
    hi = ph.v; lo = pl.v;
}

// RNE hi/lo split (used once per block for d fragments)
__device__ __forceinline__ void split_rne8(float4 x0, float4 x1, short8& hi, short8& lo) {
    float xf[8] = {x0.x, x0.y, x0.z, x0.w, x1.x, x1.y, x1.z, x1.w};
    Pack8 ph, pl;
    #pragma unroll
    for (int p = 0; p < 4; p++) {
        unsigned short ha = f2bf(xf[2 * p]), hb = f2bf(xf[2 * p + 1]);
        ph.u[p] = (unsigned int)ha | ((unsigned int)hb << 16);
        unsigned short la = f2bf(xf[2 * p] - bfbits2f(ha));
        unsigned short lb = f2bf(xf[2 * p + 1] - bfbits2f(hb));
        pl.u[p] = (unsigned int)la | ((unsigned int)lb << 16);
    }
    hi = ph.v; lo = pl.v;
}

// ---------------------------------------------------------------------------
// Kernel A: augment = [trunc(63) | time(1) | relu(conv2(conv1(x)))(128)]
// grid (94 t, 4 bh, 2 qk), 192 threads
// ---------------------------------------------------------------------------
__global__ __launch_bounds__(192) void augment_kernel(
    const float* __restrict__ q, const float* __restrict__ k,
    const float* __restrict__ W1q, const float* __restrict__ b1q,
    const float* __restrict__ W2q, const float* __restrict__ b2q,
    const float* __restrict__ W1k, const float* __restrict__ b1k,
    const float* __restrict__ W2k, const float* __restrict__ b2k,
    float* __restrict__ aug)
{
    const int t  = blockIdx.x;   // 0..93
    const int bh = blockIdx.y;   // 0..3
    const int qk = blockIdx.z;   // 0 = q, 1 = k
    const int tid = threadIdx.x;

    const float* x  = qk ? k   : q;
    const float* W1 = qk ? W1k : W1q;
    const float* b1 = qk ? b1k : b1q;
    const float* W2 = qk ? W2k : W2q;
    const float* b2 = qk ? b2k : b2q;

    __shared__ float xwin[kKS][kE];
    __shared__ float hbuf[kC1];

    const int b = bh >> 1, h = bh & 1;
    if (tid < kKS * kE) {
        int s = tid / kE, e = tid - s * kE;
        xwin[s][e] = x[(((size_t)b * kL + (t + s)) * kH + h) * kE + e];
    }
    __syncthreads();

    if (tid < kC1) {
        float acc = b1[tid];
        const float* wrow = W1 + (size_t)tid * kE * kKS;  // (o1, e, s)
        #pragma unroll 3
        for (int s = 0; s < kKS; s++)
            for (int e = 0; e < kE; e++)
                acc += xwin[s][e] * wrow[e * kKS + s];
        hbuf[tid] = acc;
    }
    __syncthreads();

    float* augrow = aug + ((size_t)(qk * kBH + bh) * kLT + t) * kC;
    if (tid < kC2) {
        float acc = b2[tid];
        const float* wrow = W2 + (size_t)tid * kC1;
        for (int o1 = 0; o1 < kC1; o1++)
            acc += hbuf[o1] * wrow[o1];
        augrow[kE + 1 + tid] = fmaxf(acc, 0.0f);
    }
    if (tid < kE) augrow[tid] = xwin[kKS - 1][tid];   // trunc = x[t+2]
    if (tid == kE) augrow[kE] = (float)t * (1.0f / 93.0f);  // time
}

// ---------------------------------------------------------------------------
// Kernel B: d[tau] = aug[tau+1]-aug[tau]; u[tau] = cumsum(d) - 0.5 d
// grid (4 bh, 2 qk), 192 threads (one per channel)
// ---------------------------------------------------------------------------
__global__ __launch_bounds__(192) void diffcum_kernel(
    const float* __restrict__ aug, float* __restrict__ dArr, float* __restrict__ uArr)
{
    const int bh = blockIdx.x, qk = blockIdx.y;
    const int c = threadIdx.x;
    const float* a = aug + (size_t)(qk * kBH + bh) * kLT * kC;
    float* dp = dArr + (size_t)(qk * kBH + bh) * kTAU * kC;
    float* up = uArr + (size_t)(qk * kBH + bh) * kTAU * kC;
    float run = 0.f;
    float prev = a[c];
    #pragma unroll 4
    for (int tau = 0; tau < kTAU; tau++) {
        float nxt = a[(size_t)(tau + 1) * kC + c];
        float dd = nxt - prev;
        run += dd;
        dp[(size_t)tau * kC + c] = dd;
        up[(size_t)tau * kC + c] = run - 0.5f * dd;
        prev = nxt;
    }
}

// ---------------------------------------------------------------------------
// Kernel C (MFMA, bilinear restructure, no LDS, no barriers):
//   F[qk,n,o] += sum_s scale(s,n) * sum_j W[o, 192 s + j] * d[n, j]
//   scale(0,n)=1 (linear part); scale(s,n)=u[n,s-1] for s>=1.
//   d hi/lo kept in registers as B-frags (loaded once); W streamed global->VGPR
//   as A-frags with truncation hi/lo split; 3-term bf16 MFMA (hh + hl + lh).
// grid (4 otile, 6 ntile, 48 = qk*ISPL + is), 256 threads
// ---------------------------------------------------------------------------
__global__ __launch_bounds__(256, 2) void sigproj_kernel(
    const float* __restrict__ Wlq,
    const float* __restrict__ Wlk,
    const float* __restrict__ dArr,
    const float* __restrict__ uArr,
    float* __restrict__ F)
{
    const int otile = blockIdx.x;
    const int ntile = blockIdx.y;
    const int zz = blockIdx.z;
    const int qk = zz / ISPL;
    const int is = zz - qk * ISPL;

    const float* __restrict__ W = qk ? Wlk : Wlq;
    const float* dB = dArr + (size_t)qk * kNCOL * kC;
    const float* uB = uArr + (size_t)qk * kNCOL * kC;

    const int tid  = threadIdx.x;
    const int lane = tid & 63;
    const int w    = tid >> 6;      // wave 0..3
    const int quad = lane >> 4;
    const int l16  = lane & 15;
    const int orow = (w & 1) * 32;
    const int ncol = (w >> 1) * 32;

    // step range for this split: NSTEP = 24*8 + 1
    const int sbase = NSTEP / ISPL, srem = NSTEP % ISPL;
    const int s0 = is * sbase + (is < srem ? is : srem);
    const int ns = sbase + (is < srem ? 1 : 0);

    // --- B-fragments (d) in registers: hi/lo RNE split, loaded once ---
    short8 bh_r[2][6], bl_r[2][6];
    const float* uptr[2];
    float nmask[2];
    #pragma unroll
    for (int b = 0; b < 2; b++) {
        const int n = ntile * 64 + ncol + b * 16 + l16;
        const bool nv = n < kNCOL;
        nmask[b] = nv ? 1.f : 0.f;
        const float* dn = dB + (size_t)(nv ? n : 0) * kC;
        uptr[b] = uB + (size_t)(nv ? n : 0) * kC;
        #pragma unroll
        for (int jb = 0; jb < 6; jb++) {
            float4 x0 = *reinterpret_cast<const float4*>(dn + jb * 32 + quad * 8);
            float4 x1 = *reinterpret_cast<const float4*>(dn + jb * 32 + quad * 8 + 4);
            if (!nv) { x0 = make_float4(0, 0, 0, 0); x1 = make_float4(0, 0, 0, 0); }
            split_rne8(x0, x1, bh_r[b][jb], bl_r[b][jb]);
        }
    }

    // per-lane W row bases (A-frag: row = l16, k = quad*8 + j)
    const float* wbase[2];
    #pragma unroll
    for (int a = 0; a < 2; a++)
        wbase[a] = W + (size_t)(otile * 64 + orow + a * 16 + l16) * kSIG + quad * 8;

    f32x4 acc[2][2];
    #pragma unroll
    for (int a = 0; a < 2; a++)
        #pragma unroll
        for (int b = 0; b < 2; b++)
            acc[a][b] = (f32x4){0.f, 0.f, 0.f, 0.f};

    for (int ci = 0; ci < ns; ci++) {
        const int s = s0 + ci;
        const int col0 = 192 * s;

        // per-step scale: 1 for linear part, else u[n, s-1]
        float uscale[2];
        #pragma unroll
        for (int b = 0; b < 2; b++)
            uscale[b] = (s == 0) ? nmask[b] : uptr[b][s - 1] * nmask[b];

        f32x4 tmp[2][2];
        #pragma unroll
        for (int a = 0; a < 2; a++)
            #pragma unroll
            for (int b = 0; b < 2; b++)
                tmp[a][b] = (f32x4){0.f, 0.f, 0.f, 0.f};

        #pragma unroll
        for (int jb = 0; jb < 6; jb++) {
            short8 ah[2], al[2];
            #pragma unroll
            for (int a = 0; a < 2; a++) {
                const float* wp = wbase[a] + col0 + jb * 32;
                float4 w0 = *reinterpret_cast<const float4*>(wp);
                float4 w1 = *reinterpret_cast<const float4*>(wp + 4);
                split_trunc8(w0, w1, ah[a], al[a]);
            }
            #pragma unroll
            for (int a = 0; a < 2; a++)
                #pragma unroll
                for (int b = 0; b < 2; b++) {
                    tmp[a][b] = __builtin_amdgcn_mfma_f32_16x16x32_bf16(
                        ah[a], bh_r[b][jb], tmp[a][b], 0, 0, 0);
                    tmp[a][b] = __builtin_amdgcn_mfma_f32_16x16x32_bf16(
                        ah[a], bl_r[b][jb], tmp[a][b], 0, 0, 0);
                    tmp[a][b] = __builtin_amdgcn_mfma_f32_16x16x32_bf16(
                        al[a], bh_r[b][jb], tmp[a][b], 0, 0, 0);
                }
        }

        #pragma unroll
        for (int a = 0; a < 2; a++)
            #pragma unroll
            for (int b = 0; b < 2; b++)
                #pragma unroll
                for (int r = 0; r < 4; r++)
                    acc[a][b][r] += uscale[b] * tmp[a][b][r];
    }

    // --- epilogue: D row(o) = quad*4 + r, col(n) = l16 (verified R3) ---
    #pragma unroll
    for (int a = 0; a < 2; a++) {
        const int o = otile * 64 + orow + a * 16 + quad * 4;
        #pragma unroll
        for (int b = 0; b < 2; b++) {
            const int n = ntile * 64 + ncol + b * 16 + l16;
            if (n < kNCOL) {
                float* dst = F + ((size_t)qk * kNCOL + n) * kOUT + o;
                #pragma unroll
                for (int r = 0; r < 4; r++)
                    atomicAdd(dst + r, acc[a][b][r]);
            }
        }
    }
}

// ---------------------------------------------------------------------------
// Kernel D: P[qk, bh, tau, o] = bias[o] + cumsum_tau F   (in place)
// grid (4 bh, 2 qk), 256 threads (one per o)
// ---------------------------------------------------------------------------
__global__ __launch_bounds__(256) void cumsum_kernel(
    float* __restrict__ F,
    const float* __restrict__ blq, const float* __restrict__ blk)
{
    const int bh = blockIdx.x, qk = blockIdx.y;
    const int o = threadIdx.x;
    float run = (qk ? blk : blq)[o];
    float* base = F + ((size_t)qk * kNCOL + bh * kTAU) * kOUT + o;
    #pragma unroll 8
    for (int tau = 0; tau < kTAU; tau++) {
        run += base[(size_t)tau * kOUT];
        base[(size_t)tau * kOUT] = run;
    }
}

// fast tanh: 1 - 2/(e^{2x}+1); saturates correctly for |x| large
__device__ __forceinline__ float tanh_fast(float x) {
    return 1.f - 2.f / (__expf(2.f * x) + 1.f);
}

// ---------------------------------------------------------------------------
// Kernel F: A[sg,t] = tanh(QP[sg]·KP[t]); Out = A @ (paired v); scatter dup rows
// grid (93 sigma, 4 bh), 128 threads.  (vagg fused: reads v directly)
// ---------------------------------------------------------------------------
__global__ __launch_bounds__(128) void attn_kernel(
    const float* __restrict__ P, const float* __restrict__ v,
    float* __restrict__ out)
{
    const int sg = blockIdx.x;   // 0..92
    const int bh = blockIdx.y;   // 0..3
    const int tid = threadIdx.x;

    __shared__ float q_l[kOUT];
    __shared__ __align__(16) float kp_l[kTAU][65];
    __shared__ float A_l[kTAU];

    const float* qrow = P + ((size_t)bh * kTAU + sg) * kOUT;
    q_l[tid] = qrow[tid];
    q_l[tid + 128] = qrow[tid + 128];

    const float* kbase = P + ((size_t)kNCOL + bh * kTAU) * kOUT;
    const int ri = tid >> 6;  // 0..1
    const int oi = tid & 63;
    float dot = 0.f;
    for (int oc = 0; oc < kOUT; oc += 64) {
        __syncthreads();
        for (int t = ri; t < kTAU; t += 2)
            kp_l[t][oi] = kbase[(size_t)t * kOUT + oc + oi];
        __syncthreads();
        if (tid < kTAU) {
            #pragma unroll 8
            for (int i = 0; i < 64; i++)
                dot += q_l[oc + i] * kp_l[tid][i];
        }
    }
    if (tid < kTAU) A_l[tid] = tanh_fast(dot);
    __syncthreads();

    if (tid < kEV) {
        const float* vb = v + (size_t)bh * kN * kEV + tid;
        float acc2 = 0.f;
        #pragma unroll 4
        for (int t = 0; t < kTAU - 1; t++)
            acc2 += A_l[t] * (vb[(size_t)(2 * t) * kEV] + vb[(size_t)(2 * t + 1) * kEV]);
        acc2 += A_l[kTAU - 1] * (vb[(size_t)184 * kEV] + vb[(size_t)185 * kEV] +
                                 vb[(size_t)186 * kEV]);
        const size_t rb = (size_t)bh * kN;
        out[(rb + 2 * sg) * kEV + tid] = acc2;
        out[(rb + 2 * sg + 1) * kEV + tid] = acc2;
        if (sg == kTAU - 1) out[(rb + 186) * kEV + tid] = acc2;
    }
}

// ---------------------------------------------------------------------------
extern "C" void kernel_launch(void* const* d_in, const int* in_sizes, int n_in,
                              void* d_out, int out_size, void* d_ws, size_t ws_size,
                              hipStream_t stream)
{
    (void)in_sizes; (void)n_in; (void)out_size; (void)ws_size;
    auto fp = [&](int i) { return (const float*)d_in[i]; };

    float* ws   = (float*)d_ws;
    float* aug  = ws + AUG_OFF;
    float* dArr = ws + D_OFF;
    float* uArr = ws + U_OFF;
    float* F    = ws + F_OFF;

    hipMemsetAsync(F, 0, F_SZ * sizeof(float), stream);

    augment_kernel<<<dim3(kLT, kBH, 2), 192, 0, stream>>>(
        fp(0), fp(1), fp(3), fp(4), fp(5), fp(6), fp(7), fp(8), fp(9), fp(10), aug);
    diffcum_kernel<<<dim3(kBH, 2), 192, 0, stream>>>(aug, dArr, uArr);
    sigproj_kernel<<<dim3(4, NTILES, 2 * ISPL), 256, 0, stream>>>(
        fp(11), fp(13), dArr, uArr, F);
    cumsum_kernel<<<dim3(kBH, 2), 256, 0, stream>>>(F, fp(12), fp(14));
    attn_kernel<<<dim3(kTAU, kBH), 128, 0, stream>>>(F, fp(2), (float*)d_out);
}

// Round 6
// 300.621 us; speedup vs baseline: 3.5051x; 1.1808x over previous
//
#include <hip/hip_runtime.h>
#include <hip/hip_bf16.h>

// Problem constants
constexpr int kB   = 2;
constexpr int kL   = 96;
constexpr int kH   = 2;
constexpr int kE   = 63;
constexpr int kOUT = 256;
constexpr int kC1  = 64;
constexpr int kC2  = 128;
constexpr int kKS  = 3;
constexpr int kC   = 192;     // E + 1 + CONV2
constexpr int kLT  = 94;      // L - KS + 1
constexpr int kN   = 187;     // 2*LT - 1
constexpr int kTAU = 93;      // distinct signature steps (odd lead-lag increments are zero)
constexpr int kEV  = 64;
constexpr int kBH  = 4;
constexpr int kSIG = 37056;   // C + C*C = 193*192
constexpr int kNCOL = kBH * kTAU;  // 372 GEMM columns per W

// sigproj tiling: 193 "steps" of K=192 (step 0 = linear d part, step s>=1 scaled by u[:,s-1])
constexpr int NSTEP = 193;
constexpr int ISPL  = 16;         // step-split: blocks = 4*6*2*16 = 768 (~3/CU)
constexpr int NTILES = 6;         // ceil(372/64)

// Workspace layout (floats)
constexpr size_t AUG_OFF  = 0;
constexpr size_t AUG_SZ   = (size_t)2 * kBH * kLT * kC;    // 144384
constexpr size_t D_OFF    = AUG_OFF + AUG_SZ;
constexpr size_t D_SZ     = (size_t)2 * kBH * kTAU * kC;   // 142848
constexpr size_t U_OFF    = D_OFF + D_SZ;
constexpr size_t F_OFF    = U_OFF + D_SZ;
constexpr size_t F_SZ     = (size_t)2 * kBH * kTAU * kOUT; // 190464

typedef __attribute__((ext_vector_type(8))) short short8;
typedef __attribute__((ext_vector_type(4))) float f32x4;

typedef const float __attribute__((address_space(1)))* gptr_t;
typedef float __attribute__((address_space(3)))* lptr_t;

__device__ __forceinline__ unsigned int fbits(float f) { return __float_as_uint(f); }
__device__ __forceinline__ float bitsf(unsigned int u) { return __uint_as_float(u); }

__device__ __forceinline__ unsigned short f2bf(float x) {
    unsigned int u = __float_as_uint(x);
    unsigned int r = (u + 0x7FFFu + ((u >> 16) & 1u)) >> 16;  // RNE
    return (unsigned short)r;
}
__device__ __forceinline__ float bfbits2f(unsigned short u) {
    return bitsf(((unsigned int)u) << 16);
}

union Pack8 { unsigned int u[4]; short8 v; };

// RNE hi/lo split of 8 fp32 -> two bf16x8
__device__ __forceinline__ void split_rne8(float4 x0, float4 x1, short8& hi, short8& lo) {
    float xf[8] = {x0.x, x0.y, x0.z, x0.w, x1.x, x1.y, x1.z, x1.w};
    Pack8 ph, pl;
    #pragma unroll
    for (int p = 0; p < 4; p++) {
        unsigned short ha = f2bf(xf[2 * p]), hb = f2bf(xf[2 * p + 1]);
        ph.u[p] = (unsigned int)ha | ((unsigned int)hb << 16);
        unsigned short la = f2bf(xf[2 * p] - bfbits2f(ha));
        unsigned short lb = f2bf(xf[2 * p + 1] - bfbits2f(hb));
        pl.u[p] = (unsigned int)la | ((unsigned int)lb << 16);
    }
    hi = ph.v; lo = pl.v;
}

// ---------------------------------------------------------------------------
// Kernel A: augment = [trunc(63) | time(1) | relu(conv2(conv1(x)))(128)]
// grid (94 t, 4 bh, 2 qk), 192 threads
// ---------------------------------------------------------------------------
__global__ __launch_bounds__(192) void augment_kernel(
    const float* __restrict__ q, const float* __restrict__ k,
    const float* __restrict__ W1q, const float* __restrict__ b1q,
    const float* __restrict__ W2q, const float* __restrict__ b2q,
    const float* __restrict__ W1k, const float* __restrict__ b1k,
    const float* __restrict__ W2k, const float* __restrict__ b2k,
    float* __restrict__ aug)
{
    const int t  = blockIdx.x;   // 0..93
    const int bh = blockIdx.y;   // 0..3
    const int qk = blockIdx.z;   // 0 = q, 1 = k
    const int tid = threadIdx.x;

    const float* x  = qk ? k   : q;
    const float* W1 = qk ? W1k : W1q;
    const float* b1 = qk ? b1k : b1q;
    const float* W2 = qk ? W2k : W2q;
    const float* b2 = qk ? b2k : b2q;

    __shared__ float xwin[kKS][kE];
    __shared__ float hbuf[kC1];

    const int b = bh >> 1, h = bh & 1;
    if (tid < kKS * kE) {
        int s = tid / kE, e = tid - s * kE;
        xwin[s][e] = x[(((size_t)b * kL + (t + s)) * kH + h) * kE + e];
    }
    __syncthreads();

    if (tid < kC1) {
        float acc = b1[tid];
        const float* wrow = W1 + (size_t)tid * kE * kKS;  // (o1, e, s)
        #pragma unroll 3
        for (int s = 0; s < kKS; s++)
            for (int e = 0; e < kE; e++)
                acc += xwin[s][e] * wrow[e * kKS + s];
        hbuf[tid] = acc;
    }
    __syncthreads();

    float* augrow = aug + ((size_t)(qk * kBH + bh) * kLT + t) * kC;
    if (tid < kC2) {
        float acc = b2[tid];
        const float* wrow = W2 + (size_t)tid * kC1;
        for (int o1 = 0; o1 < kC1; o1++)
            acc += hbuf[o1] * wrow[o1];
        augrow[kE + 1 + tid] = fmaxf(acc, 0.0f);
    }
    if (tid < kE) augrow[tid] = xwin[kKS - 1][tid];   // trunc = x[t+2]
    if (tid == kE) augrow[kE] = (float)t * (1.0f / 93.0f);  // time
}

// ---------------------------------------------------------------------------
// Kernel B: d[tau] = aug[tau+1]-aug[tau]; u[tau] = cumsum(d) - 0.5 d
// grid (4 bh, 2 qk), 192 threads (one per channel)
// ---------------------------------------------------------------------------
__global__ __launch_bounds__(192) void diffcum_kernel(
    const float* __restrict__ aug, float* __restrict__ dArr, float* __restrict__ uArr)
{
    const int bh = blockIdx.x, qk = blockIdx.y;
    const int c = threadIdx.x;
    const float* a = aug + (size_t)(qk * kBH + bh) * kLT * kC;
    float* dp = dArr + (size_t)(qk * kBH + bh) * kTAU * kC;
    float* up = uArr + (size_t)(qk * kBH + bh) * kTAU * kC;
    float run = 0.f;
    float prev = a[c];
    #pragma unroll 4
    for (int tau = 0; tau < kTAU; tau++) {
        float nxt = a[(size_t)(tau + 1) * kC + c];
        float dd = nxt - prev;
        run += dd;
        dp[(size_t)tau * kC + c] = dd;
        up[(size_t)tau * kC + c] = run - 0.5f * dd;
        prev = nxt;
    }
}

// ---------------------------------------------------------------------------
// Kernel C (MFMA, bilinear, LDS-staged W via global_load_lds DMA):
//   F[qk,n,o] += sum_s scale(s,n) * sum_j W[o, 192 s + j] * d[n, j]
//   scale(0,n)=1; scale(s,n)=u[n,s-1] for s>=1.
//   d hi/lo RNE-split held in registers; per step the 64x192 fp32 W tile is
//   DMA-staged into LDS (zero VGPR cost -> deep async pipelining), then each
//   wave ds_read_b128's its A-frags, RNE-splits, and runs 3-term bf16 MFMA.
// grid (4 otile, 6 ntile, 32 = qk*ISPL + is), 256 threads
// ---------------------------------------------------------------------------
__global__ __launch_bounds__(256) void sigproj_kernel(
    const float* __restrict__ Wlq,
    const float* __restrict__ Wlk,
    const float* __restrict__ dArr,
    const float* __restrict__ uArr,
    float* __restrict__ F)
{
    const int otile = blockIdx.x;
    const int ntile = blockIdx.y;
    const int zz = blockIdx.z;
    const int qk = zz / ISPL;
    const int is = zz - qk * ISPL;

    const float* __restrict__ W = qk ? Wlk : Wlq;
    const float* dB = dArr + (size_t)qk * kNCOL * kC;
    const float* uB = uArr + (size_t)qk * kNCOL * kC;

    // W step-tile: 64 rows x 192 cols fp32. Row stride 196 words:
    // 196 % 32 == 4 -> frag reads are 2-way bank aliased (free), 784 B = 16B-aligned.
    __shared__ __align__(16) float Ws[64][196];

    const int tid  = threadIdx.x;
    const int lane = tid & 63;
    const int w    = tid >> 6;      // wave 0..3
    const int quad = lane >> 4;
    const int l16  = lane & 15;
    const int orow = (w & 1) * 32;
    const int ncol = (w >> 1) * 32;

    // step range: NSTEP = 16*12 + 1
    const int sbase = NSTEP / ISPL, srem = NSTEP % ISPL;
    const int s0 = is * sbase + (is < srem ? is : srem);
    const int ns = sbase + (is < srem ? 1 : 0);

    // --- B-fragments (d) in registers: hi/lo RNE split, loaded once ---
    short8 bh_r[2][6], bl_r[2][6];
    const float* uptr[2];
    float nmask[2];
    #pragma unroll
    for (int b = 0; b < 2; b++) {
        const int n = ntile * 64 + ncol + b * 16 + l16;
        const bool nv = n < kNCOL;
        nmask[b] = nv ? 1.f : 0.f;
        const float* dn = dB + (size_t)(nv ? n : 0) * kC;
        uptr[b] = uB + (size_t)(nv ? n : 0) * kC;
        #pragma unroll
        for (int jb = 0; jb < 6; jb++) {
            float4 x0 = *reinterpret_cast<const float4*>(dn + jb * 32 + quad * 8);
            float4 x1 = *reinterpret_cast<const float4*>(dn + jb * 32 + quad * 8 + 4);
            if (!nv) { x0 = make_float4(0, 0, 0, 0); x1 = make_float4(0, 0, 0, 0); }
            split_rne8(x0, x1, bh_r[b][jb], bl_r[b][jb]);
        }
    }

    f32x4 acc[2][2];
    #pragma unroll
    for (int a = 0; a < 2; a++)
        #pragma unroll
        for (int b = 0; b < 2; b++)
            acc[a][b] = (f32x4){0.f, 0.f, 0.f, 0.f};

    // staging: wave w DMAs rows w*16 .. w*16+15; lanes 0..47 carry 16B each
    const int row0 = w * 16;
    const float* gbase = W + (size_t)(otile * 64 + row0) * kSIG + lane * 4;

    for (int ci = 0; ci < ns; ci++) {
        const int s = s0 + ci;
        const int col0 = 192 * s;

        __syncthreads();   // prior step's ds_reads complete -> LDS reusable
        if (lane < 48) {
            const float* gp = gbase + col0;
            #pragma unroll
            for (int i = 0; i < 16; i++)
                __builtin_amdgcn_global_load_lds(
                    (gptr_t)(gp + (size_t)i * kSIG),
                    (lptr_t)&Ws[row0 + i][0], 16, 0, 0);
        }
        __syncthreads();   // DMA drained (compiler emits vmcnt(0) before barrier)

        float uscale[2];
        #pragma unroll
        for (int b = 0; b < 2; b++)
            uscale[b] = (s == 0) ? nmask[b] : uptr[b][s - 1] * nmask[b];

        f32x4 tmp[2][2];
        #pragma unroll
        for (int a = 0; a < 2; a++)
            #pragma unroll
            for (int b = 0; b < 2; b++)
                tmp[a][b] = (f32x4){0.f, 0.f, 0.f, 0.f};

        #pragma unroll
        for (int jb = 0; jb < 6; jb++) {
            short8 ah[2], al[2];
            #pragma unroll
            for (int a = 0; a < 2; a++) {
                const float* lr = &Ws[orow + a * 16 + l16][jb * 32 + quad * 8];
                float4 w0 = *reinterpret_cast<const float4*>(lr);
                float4 w1 = *reinterpret_cast<const float4*>(lr + 4);
                split_rne8(w0, w1, ah[a], al[a]);
            }
            #pragma unroll
            for (int a = 0; a < 2; a++)
                #pragma unroll
                for (int b = 0; b < 2; b++) {
                    tmp[a][b] = __builtin_amdgcn_mfma_f32_16x16x32_bf16(
                        ah[a], bh_r[b][jb], tmp[a][b], 0, 0, 0);
                    tmp[a][b] = __builtin_amdgcn_mfma_f32_16x16x32_bf16(
                        ah[a], bl_r[b][jb], tmp[a][b], 0, 0, 0);
                    tmp[a][b] = __builtin_amdgcn_mfma_f32_16x16x32_bf16(
                        al[a], bh_r[b][jb], tmp[a][b], 0, 0, 0);
                }
        }

        #pragma unroll
        for (int a = 0; a < 2; a++)
            #pragma unroll
            for (int b = 0; b < 2; b++)
                #pragma unroll
                for (int r = 0; r < 4; r++)
                    acc[a][b][r] += uscale[b] * tmp[a][b][r];
    }

    // --- epilogue: D row(o) = quad*4 + r, col(n) = l16 (verified R3/R4) ---
    #pragma unroll
    for (int a = 0; a < 2; a++) {
        const int o = otile * 64 + orow + a * 16 + quad * 4;
        #pragma unroll
        for (int b = 0; b < 2; b++) {
            const int n = ntile * 64 + ncol + b * 16 + l16;
            if (n < kNCOL) {
                float* dst = F + ((size_t)qk * kNCOL + n) * kOUT + o;
                #pragma unroll
                for (int r = 0; r < 4; r++)
                    atomicAdd(dst + r, acc[a][b][r]);
            }
        }
    }
}

// ---------------------------------------------------------------------------
// Kernel D: P[qk, bh, tau, o] = bias[o] + cumsum_tau F   (in place)
// grid (4 bh, 2 qk), 256 threads (one per o)
// ---------------------------------------------------------------------------
__global__ __launch_bounds__(256) void cumsum_kernel(
    float* __restrict__ F,
    const float* __restrict__ blq, const float* __restrict__ blk)
{
    const int bh = blockIdx.x, qk = blockIdx.y;
    const int o = threadIdx.x;
    float run = (qk ? blk : blq)[o];
    float* base = F + ((size_t)qk * kNCOL + bh * kTAU) * kOUT + o;
    #pragma unroll 8
    for (int tau = 0; tau < kTAU; tau++) {
        run += base[(size_t)tau * kOUT];
        base[(size_t)tau * kOUT] = run;
    }
}

// fast tanh: 1 - 2/(e^{2x}+1); saturates correctly for |x| large
__device__ __forceinline__ float tanh_fast(float x) {
    return 1.f - 2.f / (__expf(2.f * x) + 1.f);
}

// ---------------------------------------------------------------------------
// Kernel F: A[sg,t] = tanh(QP[sg]·KP[t]); Out = A @ (paired v); scatter dup rows
// grid (93 sigma, 4 bh), 128 threads.  (vagg fused: reads v directly)
// ---------------------------------------------------------------------------
__global__ __launch_bounds__(128) void attn_kernel(
    const float* __restrict__ P, const float* __restrict__ v,
    float* __restrict__ out)
{
    const int sg = blockIdx.x;   // 0..92
    const int bh = blockIdx.y;   // 0..3
    const int tid = threadIdx.x;

    __shared__ float q_l[kOUT];
    __shared__ __align__(16) float kp_l[kTAU][65];
    __shared__ float A_l[kTAU];

    const float* qrow = P + ((size_t)bh * kTAU + sg) * kOUT;
    q_l[tid] = qrow[tid];
    q_l[tid + 128] = qrow[tid + 128];

    const float* kbase = P + ((size_t)kNCOL + bh * kTAU) * kOUT;
    const int ri = tid >> 6;  // 0..1
    const int oi = tid & 63;
    float dot = 0.f;
    for (int oc = 0; oc < kOUT; oc += 64) {
        __syncthreads();
        for (int t = ri; t < kTAU; t += 2)
            kp_l[t][oi] = kbase[(size_t)t * kOUT + oc + oi];
        __syncthreads();
        if (tid < kTAU) {
            #pragma unroll 8
            for (int i = 0; i < 64; i++)
                dot += q_l[oc + i] * kp_l[tid][i];
        }
    }
    if (tid < kTAU) A_l[tid] = tanh_fast(dot);
    __syncthreads();

    if (tid < kEV) {
        const float* vb = v + (size_t)bh * kN * kEV + tid;
        float acc2 = 0.f;
        #pragma unroll 4
        for (int t = 0; t < kTAU - 1; t++)
            acc2 += A_l[t] * (vb[(size_t)(2 * t) * kEV] + vb[(size_t)(2 * t + 1) * kEV]);
        acc2 += A_l[kTAU - 1] * (vb[(size_t)184 * kEV] + vb[(size_t)185 * kEV] +
                                 vb[(size_t)186 * kEV]);
        const size_t rb = (size_t)bh * kN;
        out[(rb + 2 * sg) * kEV + tid] = acc2;
        out[(rb + 2 * sg + 1) * kEV + tid] = acc2;
        if (sg == kTAU - 1) out[(rb + 186) * kEV + tid] = acc2;
    }
}

// ---------------------------------------------------------------------------
extern "C" void kernel_launch(void* const* d_in, const int* in_sizes, int n_in,
                              void* d_out, int out_size, void* d_ws, size_t ws_size,
                              hipStream_t stream)
{
    (void)in_sizes; (void)n_in; (void)out_size; (void)ws_size;
    auto fp = [&](int i) { return (const float*)d_in[i]; };

    float* ws   = (float*)d_ws;
    float* aug  = ws + AUG_OFF;
    float* dArr = ws + D_OFF;
    float* uArr = ws + U_OFF;
    float* F    = ws + F_OFF;

    hipMemsetAsync(F, 0, F_SZ * sizeof(float), stream);

    augment_kernel<<<dim3(kLT, kBH, 2), 192, 0, stream>>>(
        fp(0), fp(1), fp(3), fp(4), fp(5), fp(6), fp(7), fp(8), fp(9), fp(10), aug);
    diffcum_kernel<<<dim3(kBH, 2), 192, 0, stream>>>(aug, dArr, uArr);
    sigproj_kernel<<<dim3(4, NTILES, 2 * ISPL), 256, 0, stream>>>(
        fp(11), fp(13), dArr, uArr, F);
    cumsum_kernel<<<dim3(kBH, 2), 256, 0, stream>>>(F, fp(12), fp(14));
    attn_kernel<<<dim3(kTAU, kBH), 128, 0, stream>>>(F, fp(2), (float*)d_out);
}

// Round 8
// 267.869 us; speedup vs baseline: 3.9337x; 1.1223x over previous
//
#include <hip/hip_runtime.h>
#include <hip/hip_bf16.h>

// Problem constants
constexpr int kB   = 2;
constexpr int kL   = 96;
constexpr int kH   = 2;
constexpr int kE   = 63;
constexpr int kOUT = 256;
constexpr int kC1  = 64;
constexpr int kC2  = 128;
constexpr int kKS  = 3;
constexpr int kC   = 192;     // E + 1 + CONV2
constexpr int kLT  = 94;      // L - KS + 1
constexpr int kN   = 187;     // 2*LT - 1
constexpr int kTAU = 93;      // distinct signature steps
constexpr int kEV  = 64;
constexpr int kBH  = 4;
constexpr int kSIG = 37056;   // C + C*C = 193*192
constexpr int kNCOL = kBH * kTAU;  // 372 GEMM columns per W

// sigproj: 193 steps of K=192; step-split 16 (13 + 15*12 = 193)
constexpr int SPL = 16;

// Workspace layout (floats)
constexpr size_t AUG_OFF  = 0;
constexpr size_t AUG_SZ   = (size_t)2 * kBH * kLT * kC;    // 144384
constexpr size_t D_OFF    = AUG_OFF + AUG_SZ;
constexpr size_t D_SZ     = (size_t)2 * kBH * kTAU * kC;   // 142848
constexpr size_t U_OFF    = D_OFF + D_SZ;
constexpr size_t F_OFF    = U_OFF + D_SZ;
constexpr size_t F_SZ     = (size_t)2 * kBH * kTAU * kOUT; // 190464

typedef __attribute__((ext_vector_type(8))) short short8;
typedef __attribute__((ext_vector_type(4))) float f32x4;

typedef const float __attribute__((address_space(1)))* gptr_t;
typedef float __attribute__((address_space(3)))* lptr_t;

__device__ __forceinline__ unsigned int fbits(float f) { return __float_as_uint(f); }
__device__ __forceinline__ float bitsf(unsigned int u) { return __uint_as_float(u); }

__device__ __forceinline__ unsigned short f2bf(float x) {
    unsigned int u = __float_as_uint(x);
    unsigned int r = (u + 0x7FFFu + ((u >> 16) & 1u)) >> 16;  // RNE
    return (unsigned short)r;
}
__device__ __forceinline__ float bfbits2f(unsigned short u) {
    return bitsf(((unsigned int)u) << 16);
}

union Pack8 { unsigned int u[4]; short8 v; };

// RNE hi/lo split of 8 fp32 -> two bf16x8
__device__ __forceinline__ void split_rne8(float4 x0, float4 x1, short8& hi, short8& lo) {
    float xf[8] = {x0.x, x0.y, x0.z, x0.w, x1.x, x1.y, x1.z, x1.w};
    Pack8 ph, pl;
    #pragma unroll
    for (int p = 0; p < 4; p++) {
        unsigned short ha = f2bf(xf[2 * p]), hb = f2bf(xf[2 * p + 1]);
        ph.u[p] = (unsigned int)ha | ((unsigned int)hb << 16);
        unsigned short la = f2bf(xf[2 * p] - bfbits2f(ha));
        unsigned short lb = f2bf(xf[2 * p + 1] - bfbits2f(hb));
        pl.u[p] = (unsigned int)la | ((unsigned int)lb << 16);
    }
    hi = ph.v; lo = pl.v;
}

// ---------------------------------------------------------------------------
// Kernel A: augment = [trunc(63) | time(1) | relu(conv2(conv1(x)))(128)]
// grid (94 t, 4 bh, 2 qk), 192 threads
// ---------------------------------------------------------------------------
__global__ __launch_bounds__(192) void augment_kernel(
    const float* __restrict__ q, const float* __restrict__ k,
    const float* __restrict__ W1q, const float* __restrict__ b1q,
    const float* __restrict__ W2q, const float* __restrict__ b2q,
    const float* __restrict__ W1k, const float* __restrict__ b1k,
    const float* __restrict__ W2k, const float* __restrict__ b2k,
    float* __restrict__ aug)
{
    const int t  = blockIdx.x;   // 0..93
    const int bh = blockIdx.y;   // 0..3
    const int qk = blockIdx.z;   // 0 = q, 1 = k
    const int tid = threadIdx.x;

    const float* x  = qk ? k   : q;
    const float* W1 = qk ? W1k : W1q;
    const float* b1 = qk ? b1k : b1q;
    const float* W2 = qk ? W2k : W2q;
    const float* b2 = qk ? b2k : b2q;

    __shared__ float xwin[kKS][kE];
    __shared__ float hbuf[kC1];

    const int b = bh >> 1, h = bh & 1;
    if (tid < kKS * kE) {
        int s = tid / kE, e = tid - s * kE;
        xwin[s][e] = x[(((size_t)b * kL + (t + s)) * kH + h) * kE + e];
    }
    __syncthreads();

    if (tid < kC1) {
        float acc = b1[tid];
        const float* wrow = W1 + (size_t)tid * kE * kKS;  // (o1, e, s)
        #pragma unroll 3
        for (int s = 0; s < kKS; s++)
            for (int e = 0; e < kE; e++)
                acc += xwin[s][e] * wrow[e * kKS + s];
        hbuf[tid] = acc;
    }
    __syncthreads();

    float* augrow = aug + ((size_t)(qk * kBH + bh) * kLT + t) * kC;
    if (tid < kC2) {
        float acc = b2[tid];
        const float* wrow = W2 + (size_t)tid * kC1;
        for (int o1 = 0; o1 < kC1; o1++)
            acc += hbuf[o1] * wrow[o1];
        augrow[kE + 1 + tid] = fmaxf(acc, 0.0f);
    }
    if (tid < kE) augrow[tid] = xwin[kKS - 1][tid];   // trunc = x[t+2]
    if (tid == kE) augrow[kE] = (float)t * (1.0f / 93.0f);  // time
}

// ---------------------------------------------------------------------------
// Kernel B: d[tau] = aug[tau+1]-aug[tau]; u[tau] = cumsum(d) - 0.5 d
// grid (4 bh, 2 qk), 192 threads (one per channel)
// ---------------------------------------------------------------------------
__global__ __launch_bounds__(192) void diffcum_kernel(
    const float* __restrict__ aug, float* __restrict__ dArr, float* __restrict__ uArr)
{
    const int bh = blockIdx.x, qk = blockIdx.y;
    const int c = threadIdx.x;
    const float* a = aug + (size_t)(qk * kBH + bh) * kLT * kC;
    float* dp = dArr + (size_t)(qk * kBH + bh) * kTAU * kC;
    float* up = uArr + (size_t)(qk * kBH + bh) * kTAU * kC;
    float run = 0.f;
    float prev = a[c];
    #pragma unroll 4
    for (int tau = 0; tau < kTAU; tau++) {
        float nxt = a[(size_t)(tau + 1) * kC + c];
        float dd = nxt - prev;
        run += dd;
        dp[(size_t)tau * kC + c] = dd;
        up[(size_t)tau * kC + c] = run - 0.5f * dd;
        prev = nxt;
    }
}

// ---------------------------------------------------------------------------
// Kernel C (MFMA, bilinear, W read-once, split-once, R5-proven serial DMA):
//   F[qk,n,o] += sum_s scale(s,n) * sum_j W[o, 192 s + j] * d[n, j]
//   Block: 32 o rows x ALL 384 n (8 waves x 48 n), 16-way step split.
//   Per step (3 barriers, DMA never in flight across a consuming barrier):
//     sync; DMA 32x192 fp32 W tile -> stage; sync (drained);
//     cooperative RNE split stage -> bf16 hi/lo LDS; sync; MFMA.
// grid (8 otile, 32 = qk*SPL + is), 512 threads
// ---------------------------------------------------------------------------
__global__ __launch_bounds__(512) void sigproj_kernel(
    const float* __restrict__ Wlq,
    const float* __restrict__ Wlk,
    const float* __restrict__ dArr,
    const float* __restrict__ uArr,
    float* __restrict__ F)
{
    const int otile = blockIdx.x;      // 0..7 -> o rows [otile*32, +32)
    const int zz = blockIdx.y;
    const int qk = zz / SPL;
    const int is = zz - qk * SPL;

    const float* __restrict__ W = qk ? Wlk : Wlq;
    const float* dB = dArr + (size_t)qk * kNCOL * kC;
    const float* uB = uArr + (size_t)qk * kNCOL * kC;

    // fp32 DMA stage: 32 rows, stride 196 words
    __shared__ __align__(16) float stage[32 * 196];
    // bf16 hi/lo: 32 rows, stride 200 shorts (400 B rows, 16B-aligned)
    __shared__ __align__(16) unsigned short WhiS[32 * 200];
    __shared__ __align__(16) unsigned short WloS[32 * 200];

    const int tid  = threadIdx.x;
    const int w    = tid >> 6;      // wave 0..7
    const int lane = tid & 63;
    const int quad = lane >> 4;
    const int l16  = lane & 15;

    // step range: is=0 -> [0,13), else [12*is+1, +12)
    const int s0 = (is == 0) ? 0 : 12 * is + 1;
    const int ns = (is == 0) ? 13 : 12;

    // --- B-frags (d) in registers: 3 frags of 16 n, hi/lo RNE split ---
    short8 bh_r[3][6], bl_r[3][6];
    const float* uptr[3];
    float nmask[3];
    #pragma unroll
    for (int f = 0; f < 3; f++) {
        const int n = w * 48 + f * 16 + l16;
        const bool nv = n < kNCOL;
        nmask[f] = nv ? 1.f : 0.f;
        const float* dn = dB + (size_t)(nv ? n : 0) * kC;
        uptr[f] = uB + (size_t)(nv ? n : 0) * kC;
        #pragma unroll
        for (int jb = 0; jb < 6; jb++) {
            float4 x0 = *reinterpret_cast<const float4*>(dn + jb * 32 + quad * 8);
            float4 x1 = *reinterpret_cast<const float4*>(dn + jb * 32 + quad * 8 + 4);
            if (!nv) { x0 = make_float4(0, 0, 0, 0); x1 = make_float4(0, 0, 0, 0); }
            split_rne8(x0, x1, bh_r[f][jb], bl_r[f][jb]);
        }
    }

    f32x4 acc[2][3];
    #pragma unroll
    for (int a = 0; a < 2; a++)
        #pragma unroll
        for (int f = 0; f < 3; f++)
            acc[a][f] = (f32x4){0.f, 0.f, 0.f, 0.f};

    // DMA: wave w stages rows [w*4, w*4+4); lanes 0..47 carry 16B each
    const int row0 = w * 4;
    const float* gbase = W + (size_t)(otile * 32 + row0) * kSIG + lane * 4;

    for (int ci = 0; ci < ns; ci++) {
        const int s = s0 + ci;

        __syncthreads();   // (a) prev iter's WhiS/WloS + stage consumers done

        if (lane < 48) {
            const float* gp = gbase + (size_t)192 * s;
            #pragma unroll
            for (int i = 0; i < 4; i++)
                __builtin_amdgcn_global_load_lds(
                    (gptr_t)(gp + (size_t)i * kSIG),
                    (lptr_t)&stage[(row0 + i) * 196], 16, 0, 0);
        }
        __syncthreads();   // (b) DMA drained (vmcnt(0) before barrier; R5-proven)

        // --- split-pass: stage fp32 -> bf16 hi/lo (threads 0..383) ---
        if (tid < 384) {
            const int r = tid & 31, cb = tid >> 5;     // row, 16-col block
            const float* src = &stage[r * 196 + cb * 16];
            float4 x0 = *reinterpret_cast<const float4*>(src);
            float4 x1 = *reinterpret_cast<const float4*>(src + 4);
            float4 x2 = *reinterpret_cast<const float4*>(src + 8);
            float4 x3 = *reinterpret_cast<const float4*>(src + 12);
            short8 h0, l0, h1, l1;
            split_rne8(x0, x1, h0, l0);
            split_rne8(x2, x3, h1, l1);
            const int o16 = r * 200 + cb * 16;
            *reinterpret_cast<short8*>(&WhiS[o16]) = h0;
            *reinterpret_cast<short8*>(&WhiS[o16 + 8]) = h1;
            *reinterpret_cast<short8*>(&WloS[o16]) = l0;
            *reinterpret_cast<short8*>(&WloS[o16 + 8]) = l1;
        }
        __syncthreads();   // (c) split visible

        float uscale[3];
        #pragma unroll
        for (int f = 0; f < 3; f++)
            uscale[f] = (s == 0) ? nmask[f] : uptr[f][s - 1] * nmask[f];

        f32x4 tmp[2][3];
        #pragma unroll
        for (int a = 0; a < 2; a++)
            #pragma unroll
            for (int f = 0; f < 3; f++)
                tmp[a][f] = (f32x4){0.f, 0.f, 0.f, 0.f};

        #pragma unroll
        for (int jb = 0; jb < 6; jb++) {
            short8 ah[2], al[2];
            #pragma unroll
            for (int a = 0; a < 2; a++) {
                const int off = (a * 16 + l16) * 200 + jb * 32 + quad * 8;
                ah[a] = *reinterpret_cast<const short8*>(&WhiS[off]);
                al[a] = *reinterpret_cast<const short8*>(&WloS[off]);
            }
            #pragma unroll
            for (int a = 0; a < 2; a++)
                #pragma unroll
                for (int f = 0; f < 3; f++) {
                    tmp[a][f] = __builtin_amdgcn_mfma_f32_16x16x32_bf16(
                        ah[a], bh_r[f][jb], tmp[a][f], 0, 0, 0);
                    tmp[a][f] = __builtin_amdgcn_mfma_f32_16x16x32_bf16(
                        ah[a], bl_r[f][jb], tmp[a][f], 0, 0, 0);
                    tmp[a][f] = __builtin_amdgcn_mfma_f32_16x16x32_bf16(
                        al[a], bh_r[f][jb], tmp[a][f], 0, 0, 0);
                }
        }

        #pragma unroll
        for (int a = 0; a < 2; a++)
            #pragma unroll
            for (int f = 0; f < 3; f++)
                #pragma unroll
                for (int r = 0; r < 4; r++)
                    acc[a][f][r] += uscale[f] * tmp[a][f][r];
    }

    // --- epilogue: D row(o) = quad*4 + r, col(n) = l16 (verified R3-R5) ---
    #pragma unroll
    for (int a = 0; a < 2; a++) {
        const int o = otile * 32 + a * 16 + quad * 4;
        #pragma unroll
        for (int f = 0; f < 3; f++) {
            const int n = w * 48 + f * 16 + l16;
            if (n < kNCOL) {
                float* dst = F + ((size_t)qk * kNCOL + n) * kOUT + o;
                #pragma unroll
                for (int r = 0; r < 4; r++)
                    atomicAdd(dst + r, acc[a][f][r]);
            }
        }
    }
}

// ---------------------------------------------------------------------------
// Kernel D: P[qk, bh, tau, o] = bias[o] + cumsum_tau F   (in place)
// grid (4 bh, 2 qk), 256 threads (one per o)
// ---------------------------------------------------------------------------
__global__ __launch_bounds__(256) void cumsum_kernel(
    float* __restrict__ F,
    const float* __restrict__ blq, const float* __restrict__ blk)
{
    const int bh = blockIdx.x, qk = blockIdx.y;
    const int o = threadIdx.x;
    float run = (qk ? blk : blq)[o];
    float* base = F + ((size_t)qk * kNCOL + bh * kTAU) * kOUT + o;
    #pragma unroll 8
    for (int tau = 0; tau < kTAU; tau++) {
        run += base[(size_t)tau * kOUT];
        base[(size_t)tau * kOUT] = run;
    }
}

// fast tanh: 1 - 2/(e^{2x}+1); saturates correctly for |x| large
__device__ __forceinline__ float tanh_fast(float x) {
    return 1.f - 2.f / (__expf(2.f * x) + 1.f);
}

// ---------------------------------------------------------------------------
// Kernel F: A[sg,t] = tanh(QP[sg]·KP[t]); Out = A @ (paired v); scatter dup rows
// grid (93 sigma, 4 bh), 128 threads.
// ---------------------------------------------------------------------------
__global__ __launch_bounds__(128) void attn_kernel(
    const float* __restrict__ P, const float* __restrict__ v,
    float* __restrict__ out)
{
    const int sg = blockIdx.x;   // 0..92
    const int bh = blockIdx.y;   // 0..3
    const int tid = threadIdx.x;

    __shared__ float q_l[kOUT];
    __shared__ __align__(16) float kp_l[kTAU][65];
    __shared__ float A_l[kTAU];

    const float* qrow = P + ((size_t)bh * kTAU + sg) * kOUT;
    q_l[tid] = qrow[tid];
    q_l[tid + 128] = qrow[tid + 128];

    const float* kbase = P + ((size_t)kNCOL + bh * kTAU) * kOUT;
    const int ri = tid >> 6;  // 0..1
    const int oi = tid & 63;
    float dot = 0.f;
    for (int oc = 0; oc < kOUT; oc += 64) {
        __syncthreads();
        for (int t = ri; t < kTAU; t += 2)
            kp_l[t][oi] = kbase[(size_t)t * kOUT + oc + oi];
        __syncthreads();
        if (tid < kTAU) {
            #pragma unroll 8
            for (int i = 0; i < 64; i++)
                dot += q_l[oc + i] * kp_l[tid][i];
        }
    }
    if (tid < kTAU) A_l[tid] = tanh_fast(dot);
    __syncthreads();

    if (tid < kEV) {
        const float* vb = v + (size_t)bh * kN * kEV + tid;
        float acc2 = 0.f;
        #pragma unroll 4
        for (int t = 0; t < kTAU - 1; t++)
            acc2 += A_l[t] * (vb[(size_t)(2 * t) * kEV] + vb[(size_t)(2 * t + 1) * kEV]);
        acc2 += A_l[kTAU - 1] * (vb[(size_t)184 * kEV] + vb[(size_t)185 * kEV] +
                                 vb[(size_t)186 * kEV]);
        const size_t rb = (size_t)bh * kN;
        out[(rb + 2 * sg) * kEV + tid] = acc2;
        out[(rb + 2 * sg + 1) * kEV + tid] = acc2;
        if (sg == kTAU - 1) out[(rb + 186) * kEV + tid] = acc2;
    }
}

// ---------------------------------------------------------------------------
extern "C" void kernel_launch(void* const* d_in, const int* in_sizes, int n_in,
                              void* d_out, int out_size, void* d_ws, size_t ws_size,
                              hipStream_t stream)
{
    (void)in_sizes; (void)n_in; (void)out_size; (void)ws_size;
    auto fp = [&](int i) { return (const float*)d_in[i]; };

    float* ws   = (float*)d_ws;
    float* aug  = ws + AUG_OFF;
    float* dArr = ws + D_OFF;
    float* uArr = ws + U_OFF;
    float* F    = ws + F_OFF;

    hipMemsetAsync(F, 0, F_SZ * sizeof(float), stream);

    augment_kernel<<<dim3(kLT, kBH, 2), 192, 0, stream>>>(
        fp(0), fp(1), fp(3), fp(4), fp(5), fp(6), fp(7), fp(8), fp(9), fp(10), aug);
    diffcum_kernel<<<dim3(kBH, 2), 192, 0, stream>>>(aug, dArr, uArr);
    sigproj_kernel<<<dim3(8, 2 * SPL), 512, 0, stream>>>(
        fp(11), fp(13), dArr, uArr, F);
    cumsum_kernel<<<dim3(kBH, 2), 256, 0, stream>>>(F, fp(12), fp(14));
    attn_kernel<<<dim3(kTAU, kBH), 128, 0, stream>>>(F, fp(2), (float*)d_out);
}